// Round 4
// baseline (282.683 us; speedup 1.0000x reference)
//
#include <hip/hip_runtime.h>

// SimpleDialogGNN on MI355X — round 4.
// Identity: msg@W_msg == window(x@W_msg).
// Pipeline:
//   K0 prep          : fused {W transpose+bf16 pack} + {x -> xbf}
//   K1 gemm<1024,0>  : [u|v] = xbf @ wt1^T  (A in LDS dbuf, B global->VGPR dbuf)
//   K2 combine       : r = relu(sel(u + window(v) + biases, x)) in-place over u
//   K3 gemm<512,1>   : split-K=2 partials P0,P1 = r @ wt_out^T
//   K4 ln_final      : z = x + P0 + P1 + b_out; LayerNorm -> out
//
// ws aliasing (54 MiB):
//   region0 [ 0,16M): xbf  -> P1
//   region1 [16,32M): u    -> r (in-place) -> GEMM2 A
//   region2 [32,48M): v    -> P0
//   [48,52M): wt1   [52,54M): wt_out

typedef unsigned short u16;
typedef float floatx4 __attribute__((ext_vector_type(4)));
typedef short shortx8 __attribute__((ext_vector_type(8)));

#define T_ 1024
#define H_ 1024

__device__ __forceinline__ float bf2f(u16 v) {
    return __uint_as_float(((unsigned)v) << 16);
}
__device__ __forceinline__ u16 f2bf(float f) {  // round-to-nearest-even
    unsigned u = __float_as_uint(f);
    return (u16)((u + 0x7fffu + ((u >> 16) & 1u)) >> 16);
}
__device__ __forceinline__ void async16(const void* g, void* l) {
    __builtin_amdgcn_global_load_lds(
        (__attribute__((address_space(1))) void*)g,
        (__attribute__((address_space(3))) void*)l, 16, 0, 0);
}

// ---------------- K0: fused weight transpose-pack + x pack -------------------
// blocks [0,3072): transpose W (wid = bid>>10); blocks [3072,7168): pack x.
__global__ __launch_bounds__(256)
void prep(const float* __restrict__ Wself, const float* __restrict__ Wmsg,
          const float* __restrict__ Wout, const float* __restrict__ x,
          u16* __restrict__ wt1, u16* __restrict__ wt_out, u16* __restrict__ xbf)
{
    __shared__ float s[32][33];
    const int bid = blockIdx.x;
    if (bid < 3072) {
        const int wid = bid >> 10;
        const int rem = bid & 1023;
        const float* src = (wid == 0) ? Wself : ((wid == 1) ? Wmsg : Wout);
        const int n0 = (rem & 31) * 32, k0 = (rem >> 5) * 32;
        const int tx = threadIdx.x & 31, ty = threadIdx.x >> 5;  // 32x8
#pragma unroll
        for (int i = 0; i < 4; ++i) {
            int k = k0 + ty + 8 * i;
            s[ty + 8 * i][tx] = src[(size_t)k * H_ + n0 + tx];
        }
        __syncthreads();
#pragma unroll
        for (int i = 0; i < 4; ++i) {
            int n = n0 + ty + 8 * i;
            u16 v = f2bf(s[tx][ty + 8 * i]);
            if (wid == 0)      wt1[(size_t)n * 1024 + k0 + tx] = v;
            else if (wid == 1) wt1[(size_t)(n + 1024) * 1024 + k0 + tx] = v;
            else               wt_out[(size_t)n * 1024 + k0 + tx] = v;
        }
    } else {
        const size_t i = ((size_t)(bid - 3072) * 256 + threadIdx.x) * 8;
        float4 v0 = *(const float4*)(x + i);
        float4 v1 = *(const float4*)(x + i + 4);
        ushort4 o0, o1;
        o0.x = f2bf(v0.x); o0.y = f2bf(v0.y); o0.z = f2bf(v0.z); o0.w = f2bf(v0.w);
        o1.x = f2bf(v1.x); o1.y = f2bf(v1.y); o1.z = f2bf(v1.z); o1.w = f2bf(v1.w);
        *(ushort4*)(xbf + i) = o0;
        *(ushort4*)(xbf + i + 4) = o1;
    }
}

// ---------------- K1/K3: bf16 MFMA GEMM, A-only LDS, B in registers ----------
// A: M x 1024 row-major bf16; Bt: N x 1024 row-major bf16 (N-major).
// 128x128 tile, BK=32. A double-buffered in LDS (16 KiB) via global_load_lds;
// B fragments double-buffered in VGPRs via plain global loads (compiler vmcnt).
// Manual s_waitcnt vmcnt(6) leaves next step's 2 A-async + 4 B-loads in flight
// across the barrier.
// EPI 0: cols [0,1024)->O0, [1024,2048)->O1.  EPI 1: partial -> (z ? O1 : O0).
template <int KLEN, int EPI>
__global__ __launch_bounds__(256)
void gemm_bt(const u16* __restrict__ A, const u16* __restrict__ Bt,
             u16* __restrict__ O0, u16* __restrict__ O1)
{
    __shared__ u16 sA[2][4096];  // 16 KiB total
    const int tid = threadIdx.x;
    const int bn = blockIdx.x * 128;
    const int bm = blockIdx.y * 128;
    const int kb = blockIdx.z * KLEN;
    const int wave = tid >> 6, lane = tid & 63;
    const int wr = wave >> 1, wc = wave & 1;
    const int lrow = lane & 15, lq = lane >> 4;

    const u16* gA0 = A + (size_t)(bm + (tid >> 2)) * 1024 + kb + (tid & 3) * 8;
    const u16* gA1 = gA0 + (size_t)64 * 1024;
    // B fragment base: n = bn + wc*64 + j*16 + lrow, k = kb + s*32 + lq*8
    const u16* gB = Bt + (size_t)(bn + wc * 64 + lrow) * 1024 + kb + lq * 8;

    floatx4 acc[4][4];
#pragma unroll
    for (int i = 0; i < 4; ++i)
#pragma unroll
        for (int j = 0; j < 4; ++j)
            acc[i][j] = (floatx4){0.f, 0.f, 0.f, 0.f};

    const int aoff = (wr * 64 + lrow) * 32 + lq * 8;

    constexpr int NS = KLEN / 32;
    shortx8 breg[2][4];

    // prologue: step 0 in flight
    {
        u16* base = &sA[0][wave * 512];
        async16(gA0, base);
        async16(gA1, base + 2048);
#pragma unroll
        for (int j = 0; j < 4; ++j)
            breg[0][j] = *(const shortx8*)(gB + (size_t)j * 16384);
    }

#pragma unroll 2
    for (int s = 0; s < NS; ++s) {
        const int p = s & 1;
        if (s + 1 < NS) {
            u16* base = &sA[p ^ 1][wave * 512];
            async16(gA0 + (s + 1) * 32, base);
            async16(gA1 + (s + 1) * 32, base + 2048);
#pragma unroll
            for (int j = 0; j < 4; ++j)
                breg[(s + 1) & 1][j] =
                    *(const shortx8*)(gB + (size_t)j * 16384 + (s + 1) * 32);
            asm volatile("s_waitcnt vmcnt(6)" ::: "memory");  // step-s ops done
        } else {
            asm volatile("s_waitcnt vmcnt(0)" ::: "memory");
        }
        asm volatile("s_barrier" ::: "memory");  // A(s) visible to all waves
        const u16* pa = &sA[p][aoff];
        shortx8 av[4];
#pragma unroll
        for (int i = 0; i < 4; ++i) av[i] = *(const shortx8*)(pa + i * 512);
#pragma unroll
        for (int i = 0; i < 4; ++i)
#pragma unroll
            for (int j = 0; j < 4; ++j)
                acc[i][j] = __builtin_amdgcn_mfma_f32_16x16x32_bf16(
                    av[i], breg[s & 1][j], acc[i][j], 0, 0, 0);
        asm volatile("s_barrier" ::: "memory");  // reads of buf p done before rewrite
    }

    // epilogue — C/D mapping: col = lane&15, row = (lane>>4)*4 + reg
    u16* O;
    int cbase;
    if (EPI == 0) { O = (bn < 1024) ? O0 : O1; cbase = bn & 1023; }
    else          { O = blockIdx.z ? O1 : O0;  cbase = bn; }
#pragma unroll
    for (int i = 0; i < 4; ++i) {
        const int row0 = bm + wr * 64 + i * 16 + lq * 4;
#pragma unroll
        for (int j = 0; j < 4; ++j) {
            const int col = cbase + wc * 64 + j * 16 + lrow;
#pragma unroll
            for (int r = 0; r < 4; ++r)
                O[(size_t)(row0 + r) * 1024 + col] = f2bf(acc[i][j][r]);
        }
    }
}

// ---------------- K2: combine, no LDS, block-uniform weights ----------------
// grid (T_, B): one block per (t,b) row. w[o] and cnt are block-uniform.
__global__ __launch_bounds__(256)
void combine(u16* __restrict__ uv, const u16* __restrict__ v,
             const float* __restrict__ x, const float* __restrict__ qmask,
             const int* __restrict__ dia_len, const float* __restrict__ b_self,
             const float* __restrict__ b_msg)
{
    const int t = blockIdx.x;
    const int b = blockIdx.y;
    const int tid = threadIdx.x;
    const int dlen = dia_len[b];
    const int c4 = tid * 4;
    const size_t rowg = (size_t)b * T_ + t;

    const float* qb = qmask + (size_t)b * T_ * 2;
    const int spk_t = (qb[t * 2 + 1] > qb[t * 2]) ? 1 : 0;

    float wts[17];
    int cnt = 0;
#pragma unroll
    for (int o = 0; o < 17; ++o) {
        const int idx = t + o - 8;
        if (idx >= 0 && idx < dlen) {
            ++cnt;
            const int spk_i = (qb[idx * 2 + 1] > qb[idx * 2]) ? 1 : 0;
            wts[o] = (spk_i == spk_t) ? 1.0f : 0.5f;
        } else {
            wts[o] = 0.0f;
        }
    }
    const float inv = 1.0f / (float)(cnt > 0 ? cnt : 1);

    float a0 = 0.f, a1 = 0.f, a2 = 0.f, a3 = 0.f;
#pragma unroll
    for (int o = 0; o < 17; ++o) {
        if (wts[o] != 0.0f) {  // block-uniform branch
            const float w = wts[o] * inv;
            ushort4 vv = *(const ushort4*)(v + (rowg + (o - 8)) * 1024 + c4);
            a0 += w * bf2f(vv.x); a1 += w * bf2f(vv.y);
            a2 += w * bf2f(vv.z); a3 += w * bf2f(vv.w);
        }
    }

    float4 bs;
    {
        float4 b1 = *(const float4*)(b_self + c4);
        float4 b2 = *(const float4*)(b_msg + c4);
        bs.x = b1.x + b2.x; bs.y = b1.y + b2.y;
        bs.z = b1.z + b2.z; bs.w = b1.w + b2.w;
    }

    ushort4 u4 = *(const ushort4*)(uv + rowg * 1024 + c4);
    float4 xv = *(const float4*)(x + rowg * H_ + c4);
    const bool sel = (t < dlen);
    float h0 = bf2f(u4.x) + bs.x + a0;
    float h1 = bf2f(u4.y) + bs.y + a1;
    float h2 = bf2f(u4.z) + bs.z + a2;
    float h3 = bf2f(u4.w) + bs.w + a3;
    ushort4 outv;
    outv.x = f2bf(fmaxf(sel ? h0 : xv.x, 0.f));
    outv.y = f2bf(fmaxf(sel ? h1 : xv.y, 0.f));
    outv.z = f2bf(fmaxf(sel ? h2 : xv.z, 0.f));
    outv.w = f2bf(fmaxf(sel ? h3 : xv.w, 0.f));
    *(ushort4*)(uv + rowg * 1024 + c4) = outv;  // in-place over u
}

// ---------------- K4: z = x + P0 + P1 + b_out; LayerNorm --------------------
__global__ __launch_bounds__(256)
void ln_final(const u16* __restrict__ P0, const u16* __restrict__ P1,
              const float* __restrict__ x, const float* __restrict__ b_out,
              const float* __restrict__ gamma, const float* __restrict__ beta,
              float* __restrict__ out)
{
    const int row = blockIdx.x;
    const int tid = threadIdx.x;
    const size_t base = (size_t)row * H_ + tid * 4;
    float4 xv = *(const float4*)(x + base);
    ushort4 p0 = *(const ushort4*)(P0 + base);
    ushort4 p1 = *(const ushort4*)(P1 + base);
    float4 bo = *(const float4*)(b_out + tid * 4);
    float4 v;
    v.x = xv.x + bf2f(p0.x) + bf2f(p1.x) + bo.x;
    v.y = xv.y + bf2f(p0.y) + bf2f(p1.y) + bo.y;
    v.z = xv.z + bf2f(p0.z) + bf2f(p1.z) + bo.z;
    v.w = xv.w + bf2f(p0.w) + bf2f(p1.w) + bo.w;
    float s = v.x + v.y + v.z + v.w;
    float q = v.x * v.x + v.y * v.y + v.z * v.z + v.w * v.w;
#pragma unroll
    for (int off = 32; off > 0; off >>= 1) {
        s += __shfl_down(s, off);
        q += __shfl_down(q, off);
    }
    __shared__ float ps[4], pq[4];
    const int wave = tid >> 6, lane = tid & 63;
    if (lane == 0) { ps[wave] = s; pq[wave] = q; }
    __syncthreads();
    const float S = ps[0] + ps[1] + ps[2] + ps[3];
    const float Q = pq[0] + pq[1] + pq[2] + pq[3];
    const float mean = S * (1.0f / 1024.0f);
    const float var = Q * (1.0f / 1024.0f) - mean * mean;
    const float inv = rsqrtf(var + 1e-5f);
    float4 g = *(const float4*)(gamma + tid * 4);
    float4 bt = *(const float4*)(beta + tid * 4);
    float4 o;
    o.x = g.x * (v.x - mean) * inv + bt.x;
    o.y = g.y * (v.y - mean) * inv + bt.y;
    o.z = g.z * (v.z - mean) * inv + bt.z;
    o.w = g.w * (v.w - mean) * inv + bt.w;
    *(float4*)(out + base) = o;
}

// ---------------- launcher ---------------------------------------------------
extern "C" void kernel_launch(void* const* d_in, const int* in_sizes, int n_in,
                              void* d_out, int out_size, void* d_ws, size_t ws_size,
                              hipStream_t stream)
{
    (void)in_sizes; (void)n_in; (void)out_size; (void)ws_size;
    const float* x       = (const float*)d_in[0];
    const float* qmask   = (const float*)d_in[1];
    const int*   dia_len = (const int*)d_in[2];
    const float* W_msg   = (const float*)d_in[5];
    const float* b_msg   = (const float*)d_in[6];
    const float* W_self  = (const float*)d_in[7];
    const float* b_self  = (const float*)d_in[8];
    const float* W_out   = (const float*)d_in[9];
    const float* b_out   = (const float*)d_in[10];
    const float* gamma   = (const float*)d_in[11];
    const float* beta    = (const float*)d_in[12];
    float* out = (float*)d_out;

    char* ws = (char*)d_ws;
    u16* region0 = (u16*)ws;                           // xbf -> P1
    u16* region1 = (u16*)(ws + (size_t)(16u << 20));   // u   -> r (in-place)
    u16* region2 = (u16*)(ws + (size_t)(32u << 20));   // v   -> P0
    u16* wt1     = (u16*)(ws + (size_t)(48u << 20));   // 4 MiB
    u16* wt_out  = (u16*)(ws + (size_t)(52u << 20));   // 2 MiB

    prep<<<dim3(7168), 256, 0, stream>>>(W_self, W_msg, W_out, x,
                                         wt1, wt_out, region0);
    gemm_bt<1024, 0><<<dim3(16, 64, 1), 256, 0, stream>>>(region0, wt1,
                                                          region1, region2);
    combine<<<dim3(T_, 8), 256, 0, stream>>>(region1, region2, x, qmask,
                                             dia_len, b_self, b_msg);
    gemm_bt<512, 1><<<dim3(8, 64, 2), 256, 0, stream>>>(region1, wt_out,
                                                        region2, region0);
    ln_final<<<dim3(8192), 256, 0, stream>>>(region2, region0, x, b_out,
                                             gamma, beta, out);
}

// Round 5
// 229.597 us; speedup vs baseline: 1.2312x; 1.2312x over previous
//
#include <hip/hip_runtime.h>

// SimpleDialogGNN on MI355X — round 5.
// Identity: msg@W_msg == window(x@W_msg).
// Pipeline:
//   K0 prep          : fused {W transpose+bf16 pack} + {x -> xbf}
//   K1 gemm<1024,0>  : [u|v] = xbf @ wt1^T  (A+B LDS dbuf, XOR-swizzled layout)
//   K2 combine       : r = relu(sel(u + window(v) + biases, x)) in-place over u
//   K3 gemm<512,1>   : split-K=2 partials P0,P1 = r @ wt_out^T
//   K4 ln_final      : z = x + P0 + P1 + b_out; LayerNorm -> out
//
// GEMM LDS swizzle: stored chunk c of row r holds global k-chunk c^((r>>1)&3).
// Fragment read chunk = lq ^ ((lrow>>1)&3) -> 2-way bank aliasing only (free).
//
// ws aliasing (54 MiB):
//   region0 [ 0,16M): xbf  -> P1
//   region1 [16,32M): u    -> r (in-place) -> GEMM2 A
//   region2 [32,48M): v    -> P0
//   [48,52M): wt1   [52,54M): wt_out

typedef unsigned short u16;
typedef float floatx4 __attribute__((ext_vector_type(4)));
typedef short shortx8 __attribute__((ext_vector_type(8)));

#define T_ 1024
#define H_ 1024

__device__ __forceinline__ float bf2f(u16 v) {
    return __uint_as_float(((unsigned)v) << 16);
}
__device__ __forceinline__ u16 f2bf(float f) {  // round-to-nearest-even
    unsigned u = __float_as_uint(f);
    return (u16)((u + 0x7fffu + ((u >> 16) & 1u)) >> 16);
}
__device__ __forceinline__ void async16(const void* g, void* l) {
    __builtin_amdgcn_global_load_lds(
        (__attribute__((address_space(1))) void*)g,
        (__attribute__((address_space(3))) void*)l, 16, 0, 0);
}

// ---------------- K0: fused weight transpose-pack + x pack -------------------
// blocks [0,3072): transpose W (wid = bid>>10); blocks [3072,7168): pack x.
__global__ __launch_bounds__(256)
void prep(const float* __restrict__ Wself, const float* __restrict__ Wmsg,
          const float* __restrict__ Wout, const float* __restrict__ x,
          u16* __restrict__ wt1, u16* __restrict__ wt_out, u16* __restrict__ xbf)
{
    __shared__ float s[32][33];
    const int bid = blockIdx.x;
    if (bid < 3072) {
        const int wid = bid >> 10;
        const int rem = bid & 1023;
        const float* src = (wid == 0) ? Wself : ((wid == 1) ? Wmsg : Wout);
        const int n0 = (rem & 31) * 32, k0 = (rem >> 5) * 32;
        const int tx = threadIdx.x & 31, ty = threadIdx.x >> 5;  // 32x8
#pragma unroll
        for (int i = 0; i < 4; ++i) {
            int k = k0 + ty + 8 * i;
            s[ty + 8 * i][tx] = src[(size_t)k * H_ + n0 + tx];
        }
        __syncthreads();
#pragma unroll
        for (int i = 0; i < 4; ++i) {
            int n = n0 + ty + 8 * i;
            u16 v = f2bf(s[tx][ty + 8 * i]);
            if (wid == 0)      wt1[(size_t)n * 1024 + k0 + tx] = v;
            else if (wid == 1) wt1[(size_t)(n + 1024) * 1024 + k0 + tx] = v;
            else               wt_out[(size_t)n * 1024 + k0 + tx] = v;
        }
    } else {
        const size_t i = ((size_t)(bid - 3072) * 256 + threadIdx.x) * 8;
        float4 v0 = *(const float4*)(x + i);
        float4 v1 = *(const float4*)(x + i + 4);
        ushort4 o0, o1;
        o0.x = f2bf(v0.x); o0.y = f2bf(v0.y); o0.z = f2bf(v0.z); o0.w = f2bf(v0.w);
        o1.x = f2bf(v1.x); o1.y = f2bf(v1.y); o1.z = f2bf(v1.z); o1.w = f2bf(v1.w);
        *(ushort4*)(xbf + i) = o0;
        *(ushort4*)(xbf + i + 4) = o1;
    }
}

// ---------------- K1/K3: bf16 MFMA GEMM, dbuf LDS, XOR-swizzled --------------
// A: M x 1024 row-major bf16; Bt: N x 1024 row-major bf16 (N-major).
// 128x128 tile, BK=32, dbuf LDS; prefetch s+1 issued before raw vmcnt(4)
// + s_barrier so next-step global_load_lds stays in flight across the barrier.
// EPI 0: cols [0,1024)->O0, [1024,2048)->O1.  EPI 1: partial -> (z ? O1 : O0).
template <int KLEN, int EPI>
__global__ __launch_bounds__(256)
void gemm_bt(const u16* __restrict__ A, const u16* __restrict__ Bt,
             u16* __restrict__ O0, u16* __restrict__ O1)
{
    __shared__ u16 smem[2 * 8192];  // [buf][A 4096 u16 | B 4096 u16] = 32 KiB
    const int tid = threadIdx.x;
    const int bn = blockIdx.x * 128;
    const int bm = blockIdx.y * 128;
    const int kb = blockIdx.z * KLEN;
    const int wave = tid >> 6, lane = tid & 63;
    const int wr = wave >> 1, wc = wave & 1;
    const int lrow = lane & 15, lq = lane >> 4;

    // staging: lane tid covers LDS chunk tid (16 B) = row (tid>>2), slot (tid&3);
    // slot c stores global k-chunk c ^ ((row>>1)&3).
    const int srow = tid >> 2;                        // 0..63
    const int skc  = (tid & 3) ^ ((srow >> 1) & 3);   // swizzled global k-chunk
    const u16* gA0 = A + (size_t)(bm + srow) * 1024 + kb + skc * 8;
    const u16* gA1 = gA0 + (size_t)64 * 1024;   // rows +64: same swizzle phase
    const u16* gB0 = Bt + (size_t)(bn + srow) * 1024 + kb + skc * 8;
    const u16* gB1 = gB0 + (size_t)64 * 1024;

    floatx4 acc[4][4];
#pragma unroll
    for (int i = 0; i < 4; ++i)
#pragma unroll
        for (int j = 0; j < 4; ++j)
            acc[i][j] = (floatx4){0.f, 0.f, 0.f, 0.f};

    // fragment reads: want k-chunk lq of row (.. + lrow) -> stored slot lq^swz
    const int swz = (lrow >> 1) & 3;
    const int aoff = (wr * 64 + lrow) * 32 + ((lq ^ swz) * 8);
    const int boff = 4096 + (wc * 64 + lrow) * 32 + ((lq ^ swz) * 8);

    auto issue = [&](int s, int p) {
        u16* base = smem + p * 8192 + wave * 512;
        const int k = s * 32;
        async16(gA0 + k, base);
        async16(gA1 + k, base + 2048);
        async16(gB0 + k, base + 4096);
        async16(gB1 + k, base + 4096 + 2048);
    };

    constexpr int NS = KLEN / 32;
    issue(0, 0);
#pragma unroll 2
    for (int s = 0; s < NS; ++s) {
        const int p = s & 1;
        if (s + 1 < NS) {
            issue(s + 1, p ^ 1);
            asm volatile("s_waitcnt vmcnt(4)" ::: "memory");
        } else {
            asm volatile("s_waitcnt vmcnt(0)" ::: "memory");
        }
        asm volatile("s_barrier" ::: "memory");  // current buf loaded (all waves)
        const u16* pa = smem + p * 8192 + aoff;
        const u16* pb = smem + p * 8192 + boff;
        shortx8 av[4], bv[4];
#pragma unroll
        for (int i = 0; i < 4; ++i) av[i] = *(const shortx8*)(pa + i * 512);
#pragma unroll
        for (int j = 0; j < 4; ++j) bv[j] = *(const shortx8*)(pb + j * 512);
#pragma unroll
        for (int i = 0; i < 4; ++i)
#pragma unroll
            for (int j = 0; j < 4; ++j)
                acc[i][j] = __builtin_amdgcn_mfma_f32_16x16x32_bf16(
                    av[i], bv[j], acc[i][j], 0, 0, 0);
        asm volatile("s_barrier" ::: "memory");  // reads done before buf reload
    }

    // epilogue — C/D mapping: col = lane&15, row = (lane>>4)*4 + reg
    u16* O;
    int cbase;
    if (EPI == 0) { O = (bn < 1024) ? O0 : O1; cbase = bn & 1023; }
    else          { O = blockIdx.z ? O1 : O0;  cbase = bn; }
#pragma unroll
    for (int i = 0; i < 4; ++i) {
        const int row0 = bm + wr * 64 + i * 16 + lq * 4;
#pragma unroll
        for (int j = 0; j < 4; ++j) {
            const int col = cbase + wc * 64 + j * 16 + lrow;
#pragma unroll
            for (int r = 0; r < 4; ++r)
                O[(size_t)(row0 + r) * 1024 + col] = f2bf(acc[i][j][r]);
        }
    }
}

// ---------------- K2: combine, no LDS, block-uniform weights ----------------
// grid (T_, B): one block per (t,b) row. w[o] and cnt are block-uniform.
__global__ __launch_bounds__(256)
void combine(u16* __restrict__ uv, const u16* __restrict__ v,
             const float* __restrict__ x, const float* __restrict__ qmask,
             const int* __restrict__ dia_len, const float* __restrict__ b_self,
             const float* __restrict__ b_msg)
{
    const int t = blockIdx.x;
    const int b = blockIdx.y;
    const int tid = threadIdx.x;
    const int dlen = dia_len[b];
    const int c4 = tid * 4;
    const size_t rowg = (size_t)b * T_ + t;

    const float* qb = qmask + (size_t)b * T_ * 2;
    const int spk_t = (qb[t * 2 + 1] > qb[t * 2]) ? 1 : 0;

    float wts[17];
    int cnt = 0;
#pragma unroll
    for (int o = 0; o < 17; ++o) {
        const int idx = t + o - 8;
        if (idx >= 0 && idx < dlen) {
            ++cnt;
            const int spk_i = (qb[idx * 2 + 1] > qb[idx * 2]) ? 1 : 0;
            wts[o] = (spk_i == spk_t) ? 1.0f : 0.5f;
        } else {
            wts[o] = 0.0f;
        }
    }
    const float inv = 1.0f / (float)(cnt > 0 ? cnt : 1);

    float a0 = 0.f, a1 = 0.f, a2 = 0.f, a3 = 0.f;
#pragma unroll
    for (int o = 0; o < 17; ++o) {
        if (wts[o] != 0.0f) {  // block-uniform branch
            const float w = wts[o] * inv;
            ushort4 vv = *(const ushort4*)(v + (rowg + (o - 8)) * 1024 + c4);
            a0 += w * bf2f(vv.x); a1 += w * bf2f(vv.y);
            a2 += w * bf2f(vv.z); a3 += w * bf2f(vv.w);
        }
    }

    float4 bs;
    {
        float4 b1 = *(const float4*)(b_self + c4);
        float4 b2 = *(const float4*)(b_msg + c4);
        bs.x = b1.x + b2.x; bs.y = b1.y + b2.y;
        bs.z = b1.z + b2.z; bs.w = b1.w + b2.w;
    }

    ushort4 u4 = *(const ushort4*)(uv + rowg * 1024 + c4);
    float4 xv = *(const float4*)(x + rowg * H_ + c4);
    const bool sel = (t < dlen);
    float h0 = bf2f(u4.x) + bs.x + a0;
    float h1 = bf2f(u4.y) + bs.y + a1;
    float h2 = bf2f(u4.z) + bs.z + a2;
    float h3 = bf2f(u4.w) + bs.w + a3;
    ushort4 outv;
    outv.x = f2bf(fmaxf(sel ? h0 : xv.x, 0.f));
    outv.y = f2bf(fmaxf(sel ? h1 : xv.y, 0.f));
    outv.z = f2bf(fmaxf(sel ? h2 : xv.z, 0.f));
    outv.w = f2bf(fmaxf(sel ? h3 : xv.w, 0.f));
    *(ushort4*)(uv + rowg * 1024 + c4) = outv;  // in-place over u
}

// ---------------- K4: z = x + P0 + P1 + b_out; LayerNorm --------------------
__global__ __launch_bounds__(256)
void ln_final(const u16* __restrict__ P0, const u16* __restrict__ P1,
              const float* __restrict__ x, const float* __restrict__ b_out,
              const float* __restrict__ gamma, const float* __restrict__ beta,
              float* __restrict__ out)
{
    const int row = blockIdx.x;
    const int tid = threadIdx.x;
    const size_t base = (size_t)row * H_ + tid * 4;
    float4 xv = *(const float4*)(x + base);
    ushort4 p0 = *(const ushort4*)(P0 + base);
    ushort4 p1 = *(const ushort4*)(P1 + base);
    float4 bo = *(const float4*)(b_out + tid * 4);
    float4 v;
    v.x = xv.x + bf2f(p0.x) + bf2f(p1.x) + bo.x;
    v.y = xv.y + bf2f(p0.y) + bf2f(p1.y) + bo.y;
    v.z = xv.z + bf2f(p0.z) + bf2f(p1.z) + bo.z;
    v.w = xv.w + bf2f(p0.w) + bf2f(p1.w) + bo.w;
    float s = v.x + v.y + v.z + v.w;
    float q = v.x * v.x + v.y * v.y + v.z * v.z + v.w * v.w;
#pragma unroll
    for (int off = 32; off > 0; off >>= 1) {
        s += __shfl_down(s, off);
        q += __shfl_down(q, off);
    }
    __shared__ float ps[4], pq[4];
    const int wave = tid >> 6, lane = tid & 63;
    if (lane == 0) { ps[wave] = s; pq[wave] = q; }
    __syncthreads();
    const float S = ps[0] + ps[1] + ps[2] + ps[3];
    const float Q = pq[0] + pq[1] + pq[2] + pq[3];
    const float mean = S * (1.0f / 1024.0f);
    const float var = Q * (1.0f / 1024.0f) - mean * mean;
    const float inv = rsqrtf(var + 1e-5f);
    float4 g = *(const float4*)(gamma + tid * 4);
    float4 bt = *(const float4*)(beta + tid * 4);
    float4 o;
    o.x = g.x * (v.x - mean) * inv + bt.x;
    o.y = g.y * (v.y - mean) * inv + bt.y;
    o.z = g.z * (v.z - mean) * inv + bt.z;
    o.w = g.w * (v.w - mean) * inv + bt.w;
    *(float4*)(out + base) = o;
}

// ---------------- launcher ---------------------------------------------------
extern "C" void kernel_launch(void* const* d_in, const int* in_sizes, int n_in,
                              void* d_out, int out_size, void* d_ws, size_t ws_size,
                              hipStream_t stream)
{
    (void)in_sizes; (void)n_in; (void)out_size; (void)ws_size;
    const float* x       = (const float*)d_in[0];
    const float* qmask   = (const float*)d_in[1];
    const int*   dia_len = (const int*)d_in[2];
    const float* W_msg   = (const float*)d_in[5];
    const float* b_msg   = (const float*)d_in[6];
    const float* W_self  = (const float*)d_in[7];
    const float* b_self  = (const float*)d_in[8];
    const float* W_out   = (const float*)d_in[9];
    const float* b_out   = (const float*)d_in[10];
    const float* gamma   = (const float*)d_in[11];
    const float* beta    = (const float*)d_in[12];
    float* out = (float*)d_out;

    char* ws = (char*)d_ws;
    u16* region0 = (u16*)ws;                           // xbf -> P1
    u16* region1 = (u16*)(ws + (size_t)(16u << 20));   // u   -> r (in-place)
    u16* region2 = (u16*)(ws + (size_t)(32u << 20));   // v   -> P0
    u16* wt1     = (u16*)(ws + (size_t)(48u << 20));   // 4 MiB
    u16* wt_out  = (u16*)(ws + (size_t)(52u << 20));   // 2 MiB

    prep<<<dim3(7168), 256, 0, stream>>>(W_self, W_msg, W_out, x,
                                         wt1, wt_out, region0);
    gemm_bt<1024, 0><<<dim3(16, 64, 1), 256, 0, stream>>>(region0, wt1,
                                                          region1, region2);
    combine<<<dim3(T_, 8), 256, 0, stream>>>(region1, region2, x, qmask,
                                             dia_len, b_self, b_msg);
    gemm_bt<512, 1><<<dim3(8, 64, 2), 256, 0, stream>>>(region1, wt_out,
                                                        region2, region0);
    ln_final<<<dim3(8192), 256, 0, stream>>>(region2, region0, x, b_out,
                                             gamma, beta, out);
}